// Round 2
// baseline (324.365 us; speedup 1.0000x reference)
//
#include <hip/hip_runtime.h>
#include <math.h>

#define LSEQ 1024
#define NB 16
#define NC 12
#define NH 256
#define NM 32
#define NS 3
#define TWO_PI 6.283185307179586f

// ---- workspace layout (float offsets) ----
#define OFF_MEANS 0          // 192
#define OFF_STDEV 192        // 192
#define OFF_EPART 384        // 96*256 = 24576
#define OFF_WT_RE 24960      // S*K*N = 24576
#define OFF_WT_IM 49536      // 24576
#define OFF_V     74112      // S*N*L = 786432
#define OFF_P0    860544     // S*N*N = 196608
#define OFF_P1    1057152    // 196608
#define OFF_H     1253760    // 1024
// total ~1254784 floats ~ 5 MB

__device__ __forceinline__ float block_reduce_sum(float v, float* sbuf) {
  int t = threadIdx.x;
  sbuf[t] = v; __syncthreads();
  for (int off = 128; off > 0; off >>= 1) {
    if (t < off) sbuf[t] += sbuf[t + off];
    __syncthreads();
  }
  float r = sbuf[0];
  __syncthreads();
  return r;
}

// fused front: stats (blk<192) | ebar partials (192..287) | V init (288) | H/out init (289)
__global__ __launch_bounds__(256) void k_front(const float* __restrict__ x,
                                               const float* __restrict__ Bv,
                                               const float* __restrict__ ev,
                                               const float* __restrict__ b_fc,
                                               float* __restrict__ means,
                                               float* __restrict__ stdev,
                                               float* __restrict__ epart,
                                               float* __restrict__ V,
                                               float* __restrict__ H,
                                               float* __restrict__ out) {
  __shared__ float xs[LSEQ];
  __shared__ float red[256];
  int blk = blockIdx.x;
  int t = threadIdx.x;
  if (blk < 192) {
    int b = blk / NC, c = blk % NC;
    for (int e = 0; e < 4; ++e) {
      int tau = t + 256 * e;
      xs[tau] = x[((size_t)b * LSEQ + tau) * NC + c];
    }
    __syncthreads();
    float p = 0.f;
    for (int e = 0; e < 4; ++e) p += xs[t + 256 * e];
    float sum = block_reduce_sum(p, red);
    float mean = sum * (1.0f / LSEQ);
    float q = 0.f;
    for (int e = 0; e < 4; ++e) { float d = xs[t + 256 * e] - mean; q += d * d; }
    float sq = block_reduce_sum(q, red);
    if (t == 0) {
      means[blk] = mean;
      stdev[blk] = sqrtf(sq * (1.0f / LSEQ) + 1e-5f);
    }
  } else if (blk < 288) {
    int bb = blk - 192;          // s*32 + chunk
    int s = bb >> 5, ch = bb & 31;
    float acc = 0.f;
    const float* base = ev + (size_t)s * LSEQ * NH + (size_t)ch * 32 * NH + t;
    for (int l = 0; l < 32; ++l) acc += base[(size_t)l * NH];
    epart[(size_t)bb * NH + t] = acc;
  } else if (blk == 288) {
    for (int e = 0; e < 3; ++e) {
      int idx = t + 256 * e;     // s*NH + i
      V[(size_t)idx * LSEQ] = Bv[idx];
    }
  } else {
    for (int e = 0; e < 4; ++e) H[t + 256 * e] = 0.0f;
    if (t < NB * 5) out[t] = b_fc[t % 5];
  }
}

// wt[s,k,i] = sum_o ebar[s,o] * w_spec[s,i,o,k]; ebar recomputed from partials per block
__global__ __launch_bounds__(256) void k_wtilde(const float* __restrict__ wre,
                                                const float* __restrict__ wim,
                                                const float* __restrict__ epart,
                                                float* __restrict__ wt_re,
                                                float* __restrict__ wt_im) {
  int blk = blockIdx.x; int s = blk / NH, i = blk % NH;
  int t = threadIdx.x;
  __shared__ float ebs[NH];
  __shared__ float sr[256], si_[256];
  float eb = 0.f;
  for (int ch = 0; ch < 32; ++ch) eb += epart[((size_t)(s * 32 + ch)) * NH + t];
  ebs[t] = eb * (1.0f / LSEQ);
  __syncthreads();
  const float* br = wre + (size_t)(s * NH + i) * NH * NM;
  const float* bi = wim + (size_t)(s * NH + i) * NH * NM;
  float accR = 0.f, accI = 0.f;
  int g = t >> 5;
  for (int it = 0; it < 32; ++it) {
    int o = g + 8 * it;
    float e = ebs[o];
    int idx = t + 256 * it;   // == o*32 + k, coalesced
    accR += e * br[idx];
    accI += e * bi[idx];
  }
  sr[t] = accR; si_[t] = accI;
  __syncthreads();
  if (t < 32) {
    float aR = 0.f, aI = 0.f;
    for (int gg = 0; gg < 8; ++gg) { aR += sr[gg * 32 + t]; aI += si_[gg * 32 + t]; }
    wt_re[(size_t)(s * NM + t) * NH + i] = aR;
    wt_im[(size_t)(s * NM + t) * NH + i] = aI;
  }
}

// one doubling step: job0: V[:, m..2m-1] = P @ V[:, 0..m-1]; job1: Pnext = P @ P
__global__ __launch_bounds__(256) void k_gemm_step(const float* __restrict__ Pcur,
                                                   float* __restrict__ Pnext,
                                                   float* __restrict__ V,
                                                   int m, int doSquare) {
  int z = blockIdx.z; int s = z >> 1, job = z & 1;
  const float *Amat, *Bmat; float* Cmat; int ncols, ldb, ldc;
  if (job == 0) {
    Amat = Pcur + (size_t)s * NH * NH;
    Bmat = V + (size_t)s * NH * LSEQ;
    Cmat = V + (size_t)s * NH * LSEQ + m;
    ncols = m; ldb = LSEQ; ldc = LSEQ;
  } else {
    if (!doSquare) return;
    Amat = Pcur + (size_t)s * NH * NH;
    Bmat = Amat;
    Cmat = Pnext + (size_t)s * NH * NH;
    ncols = NH; ldb = NH; ldc = NH;
  }
  int bx = blockIdx.x, by = blockIdx.y;
  if (bx * 64 >= ncols) return;
  __shared__ float As[32][68];
  __shared__ float Bs[32][68];
  int tid = threadIdx.x;
  int tx = tid & 15, ty = tid >> 4;
  float acc[4][4] = {{0.f}};
  int row0 = by * 64, col0 = bx * 64;
  int kkA = tid & 31, iA = tid >> 5;       // A: 8 rows per thread
  int jB = tid & 63, kkB = tid >> 6;       // B: 8 k-rows per thread
  for (int k0 = 0; k0 < NH; k0 += 32) {
    #pragma unroll
    for (int p = 0; p < 8; ++p)
      As[kkA][iA + 8 * p] = Amat[(size_t)(row0 + iA + 8 * p) * NH + k0 + kkA];
    #pragma unroll
    for (int p = 0; p < 8; ++p) {
      int col = col0 + jB;
      Bs[kkB + 4 * p][jB] = (col < ncols) ? Bmat[(size_t)(k0 + kkB + 4 * p) * ldb + col] : 0.0f;
    }
    __syncthreads();
    #pragma unroll
    for (int kk = 0; kk < 32; ++kk) {
      float4 av = *(const float4*)&As[kk][ty * 4];
      float4 bv = *(const float4*)&Bs[kk][tx * 4];
      acc[0][0] += av.x * bv.x; acc[0][1] += av.x * bv.y; acc[0][2] += av.x * bv.z; acc[0][3] += av.x * bv.w;
      acc[1][0] += av.y * bv.x; acc[1][1] += av.y * bv.y; acc[1][2] += av.y * bv.z; acc[1][3] += av.y * bv.w;
      acc[2][0] += av.z * bv.x; acc[2][1] += av.z * bv.y; acc[2][2] += av.z * bv.z; acc[2][3] += av.z * bv.w;
      acc[3][0] += av.w * bv.x; acc[3][1] += av.w * bv.y; acc[3][2] += av.w * bv.z; acc[3][3] += av.w * bv.w;
    }
    __syncthreads();
  }
  for (int ii = 0; ii < 4; ++ii) {
    int r = row0 + ty * 4 + ii;
    for (int jj = 0; jj < 4; ++jj) {
      int c2 = col0 + tx * 4 + jj;
      if (c2 < ncols) Cmat[(size_t)r * ldc + c2] = acc[ii][jj];
    }
  }
}

// fused: ut row (s,k) -> twiddle -> in-LDS prefix scan -> atomic H contribution
__global__ __launch_bounds__(256) void k_utscan(const float* __restrict__ wt_re,
                                                const float* __restrict__ wt_im,
                                                const float* __restrict__ V,
                                                const float* __restrict__ w_mlp,
                                                float* __restrict__ H) {
  int blk = blockIdx.x;   // s*NM + k
  int s = blk / NM, k = blk & 31;
  int t = threadIdx.x;
  __shared__ float sr[LSEQ], si_[LSEQ];
  __shared__ float cr[256], ci[256];
  // phase A: ut[d] = sum_i wt[i] * V[i,d], d = t + 256e
  const float* wr = wt_re + (size_t)blk * NH;
  const float* wi_ = wt_im + (size_t)blk * NH;
  const float* Vs = V + (size_t)s * NH * LSEQ;
  float ar[4] = {0.f, 0.f, 0.f, 0.f}, ai[4] = {0.f, 0.f, 0.f, 0.f};
  for (int i = 0; i < NH; ++i) {
    float a = wr[i], b = wi_[i];
    const float* vrow = Vs + (size_t)i * LSEQ + t;
    #pragma unroll
    for (int e = 0; e < 4; ++e) {
      float v = vrow[256 * e];
      ar[e] += a * v; ai[e] += b * v;
    }
  }
  // twiddle into shared
  for (int e = 0; e < 4; ++e) {
    int d = t + 256 * e;
    int frac = (k * d) & 1023;
    float ang = -(TWO_PI / 1024.0f) * (float)frac;
    float sn, csn; sincosf(ang, &sn, &csn);
    sr[d] = ar[e] * csn - ai[e] * sn;
    si_[d] = ar[e] * sn + ai[e] * csn;
  }
  __syncthreads();
  // phase B: prefix scan (4 serial per thread + Hillis-Steele over 256)
  float lr[4], li[4], rr = 0.f, ii = 0.f;
  for (int e = 0; e < 4; ++e) {
    rr += sr[4 * t + e]; ii += si_[4 * t + e];
    lr[e] = rr; li[e] = ii;
  }
  cr[t] = rr; ci[t] = ii;
  __syncthreads();
  for (int off = 1; off < 256; off <<= 1) {
    float pr = 0.f, pi = 0.f;
    if (t >= off) { pr = cr[t - off]; pi = ci[t - off]; }
    __syncthreads();
    cr[t] += pr; ci[t] += pi;
    __syncthreads();
  }
  float offr = (t > 0) ? cr[t - 1] : 0.0f;
  float offi = (t > 0) ? ci[t - 1] : 0.0f;
  for (int e = 0; e < 4; ++e) {
    sr[4 * t + e] = lr[e] + offr;
    si_[4 * t + e] = li[e] + offi;
  }
  __syncthreads();
  // phase C: H[tau] += wm * coef * Re(S[1023-tau] * e^{-i w_k (tau+1)})
  float wm = w_mlp[s];
  float coef = wm * ((k == 0) ? 1.0f : 2.0f) * (1.0f / LSEQ);
  for (int e = 0; e < 4; ++e) {
    int tau = t + 256 * e;
    int mIdx = 1023 - tau;
    int frac = (k * (tau + 1)) & 1023;
    float ang = -(TWO_PI / 1024.0f) * (float)frac;
    float sn, csn; sincosf(ang, &sn, &csn);
    float val = coef * (sr[mIdx] * csn - si_[mIdx] * sn);
    atomicAdd(&H[tau], val);
  }
}

// feat per (b,c) + atomic accumulate into out (pre-initialized to b_fc)
__global__ __launch_bounds__(256) void k_feat(const float* __restrict__ x,
                                              const float* __restrict__ means,
                                              const float* __restrict__ stdev,
                                              const float* __restrict__ aw,
                                              const float* __restrict__ ab,
                                              const float* __restrict__ b_mlp,
                                              const float* __restrict__ H,
                                              const float* __restrict__ w_fc,
                                              float* __restrict__ out) {
  int bc = blockIdx.x; int b = bc / NC, c = bc % NC;
  __shared__ float red[256];
  int t = threadIdx.x;
  float mn = means[bc], sd = stdev[bc];
  float w = aw[c], bb = ab[c];
  float acc = 0.f;
  for (int e = 0; e < 4; ++e) {
    int tau = t + 256 * e;
    float xv = x[((size_t)b * LSEQ + tau) * NC + c];
    float f = (xv - mn) / sd * w + bb;
    acc += f * H[tau];
  }
  float sum = block_reduce_sum(acc, red);
  if (t == 0) {
    float mr = sum + b_mlp[0];
    float featv = (mr - bb) / (w + 1e-10f) * sd + mn;
    #pragma unroll
    for (int d = 0; d < 5; ++d)
      atomicAdd(&out[b * 5 + d], featv * w_fc[d * NC + c]);
  }
}

extern "C" void kernel_launch(void* const* d_in, const int* in_sizes, int n_in,
                              void* d_out, int out_size, void* d_ws, size_t ws_size,
                              hipStream_t stream) {
  const float* x_enc   = (const float*)d_in[0];
  const float* aw      = (const float*)d_in[1];
  const float* ab      = (const float*)d_in[2];
  const float* wre     = (const float*)d_in[3];
  const float* wim     = (const float*)d_in[4];
  const float* w_mlp   = (const float*)d_in[5];
  const float* b_mlp   = (const float*)d_in[6];
  const float* w_fc    = (const float*)d_in[7];
  const float* b_fc    = (const float*)d_in[8];
  const float* A_mats  = (const float*)d_in[9];
  const float* B_vecs  = (const float*)d_in[10];
  const float* ev      = (const float*)d_in[11];

  float* ws    = (float*)d_ws;
  float* means = ws + OFF_MEANS;
  float* stdev = ws + OFF_STDEV;
  float* epart = ws + OFF_EPART;
  float* wt_re = ws + OFF_WT_RE;
  float* wt_im = ws + OFF_WT_IM;
  float* V     = ws + OFF_V;
  float* P0    = ws + OFF_P0;
  float* P1    = ws + OFF_P1;
  float* H     = ws + OFF_H;
  float* out   = (float*)d_out;

  k_front<<<290, 256, 0, stream>>>(x_enc, B_vecs, ev, b_fc, means, stdev, epart, V, H, out);
  k_wtilde<<<NS * NH, 256, 0, stream>>>(wre, wim, epart, wt_re, wt_im);

  // Krylov doubling: V_{2m} = [V_m | P_m V_m], P_{2m} = P_m^2
  const float* Pc = A_mats;  // P_1 = A
  float* Pn = P0;
  for (int m = 1; m <= 512; m <<= 1) {
    int doSq = (m < 512);
    k_gemm_step<<<dim3(8, 4, 6), 256, 0, stream>>>(Pc, Pn, V, m, doSq);
    Pc = Pn;
    Pn = (Pn == P0) ? P1 : P0;
  }

  k_utscan<<<NS * NM, 256, 0, stream>>>(wt_re, wt_im, V, w_mlp, H);
  k_feat<<<192, 256, 0, stream>>>(x_enc, means, stdev, aw, ab, b_mlp, H, w_fc, out);
}